// Round 16
// baseline (162.863 us; speedup 1.0000x reference)
//
#include <hip/hip_runtime.h>
#include <math.h>

constexpr int B_  = 64;
constexpr int LQ_ = 64;
constexpr int LS_ = 512;
constexpr int S_  = 512;
#define NEGV (-1e6f)
#define MARGIN 0.0625f

typedef __attribute__((ext_vector_type(8))) short bf16x8;
typedef __attribute__((ext_vector_type(4))) float f32x4;

__device__ inline unsigned short f2bf_rn(float x) {
    unsigned u = __builtin_bit_cast(unsigned, x);
    unsigned r = (u + 0x7FFFu + ((u >> 16) & 1u)) >> 16;
    return (unsigned short)r;
}

// -------- Kernel 1: qpool + one inter matrix per block (grid (B,2)) --------
__global__ __launch_bounds__(512)
void qpool_inter_kernel(const float* __restrict__ eq, const int* __restrict__ qlen,
                        const float* __restrict__ W_qa,
                        const float* __restrict__ W_qsi, const float* __restrict__ b_qsi,
                        const float* __restrict__ W_qei, const float* __restrict__ b_qei,
                        float* __restrict__ q_state,
                        float* __restrict__ qsi, float* __restrict__ qei)
{
    int b = blockIdx.x;
    int which = blockIdx.y;
    const float* W  = which ? W_qei : W_qsi;
    const float* bi = which ? b_qei : b_qsi;
    float*       o  = which ? qei   : qsi;

    int t = threadIdx.x, lane = t & 63, w = t >> 6;
    __shared__ float att[LQ_], wsm[LQ_], qs[S_];
    __shared__ float red[8][S_];
    const float* eqb = eq + (size_t)b * LQ_ * S_;

    #pragma unroll
    for (int k = 0; k < 8; ++k) {
        int q = w + 8 * k;
        const float* row = eqb + q * S_;
        float s = 0.f;
        #pragma unroll
        for (int j = 0; j < 8; ++j)
            s = fmaf(row[lane + 64 * j], W_qa[lane + 64 * j], s);
        #pragma unroll
        for (int off = 32; off >= 1; off >>= 1)
            s += __shfl_xor(s, off);
        if (lane == 0) att[q] = s;
    }
    __syncthreads();

    if (w == 0) {
        int L = qlen[b];
        float v = att[lane] + ((lane < L) ? 0.f : NEGV);
        float m = v;
        #pragma unroll
        for (int off = 32; off >= 1; off >>= 1)
            m = fmaxf(m, __shfl_xor(m, off));
        float e = expf(v - m);
        float sum = e;
        #pragma unroll
        for (int off = 32; off >= 1; off >>= 1)
            sum += __shfl_xor(sum, off);
        wsm[lane] = e / sum;
    }
    __syncthreads();

    {
        float acc = 0.f;
        #pragma unroll 8
        for (int q = 0; q < LQ_; ++q)
            acc = fmaf(wsm[q], eqb[q * S_ + t], acc);
        qs[t] = acc;
        if (which == 0) q_state[b * S_ + t] = acc;
    }
    __syncthreads();

    {
        float z[8];
        #pragma unroll
        for (int k = 0; k < 8; ++k) z[k] = 0.f;
        const int d0 = w * 64;
        #pragma unroll 4
        for (int dd = 0; dd < 64; ++dd) {
            int d = d0 + dd;
            float q = qs[d];
            const float* row = W + (size_t)d * S_ + lane;
            #pragma unroll
            for (int k = 0; k < 8; ++k)
                z[k] = fmaf(q, row[k * 64], z[k]);
        }
        #pragma unroll
        for (int k = 0; k < 8; ++k) red[w][k * 64 + lane] = z[k];
    }
    __syncthreads();
    {
        float acc = bi[t];
        #pragma unroll
        for (int ww = 0; ww < 8; ++ww) acc += red[ww][t];
        o[b * S_ + t] = acc;
    }
}

// ---------------- candidate selection ----------------
__device__ inline int select_cands(const float* s_l, int t, int lane, int w,
                                   float* wred, int* wcnt, int* cand)
{
    float v = s_l[t];
    #pragma unroll
    for (int off = 32; off >= 1; off >>= 1)
        v = fmaxf(v, __shfl_xor(v, off));
    if (lane == 0) wred[w] = v;
    __syncthreads();
    float m = wred[0];
    #pragma unroll
    for (int k = 1; k < 8; ++k) m = fmaxf(m, wred[k]);
    float th = m - MARGIN;
    bool flag = s_l[t] >= th;
    unsigned long long bal = __ballot(flag);
    int rank = __popcll(bal & ((1ull << lane) - 1ull));
    if (lane == 0) wcnt[w] = (int)__popcll(bal);
    __syncthreads();
    int off = 0, total = 0;
    #pragma unroll
    for (int k = 0; k < 8; ++k) { if (k < w) off += wcnt[k]; total += wcnt[k]; }
    if (flag) { int pos = off + rank; if (pos < 8) cand[pos] = t; }
    __syncthreads();
    return total < 8 ? total : 8;
}

// ---------------- Kernel P2: start-pass folded weight prep (bf16, RN) ------
// Wc layout: [b][i][kc][col][8] shorts; base = b*262144 + i*16384 + col*8.
__global__ __launch_bounds__(512)
void prep_start_kernel(const float* __restrict__ W, const float* __restrict__ q_state,
                       short* __restrict__ Wc)
{
    int bid = blockIdx.x;
    int i = bid >> 6, b = bid & 63;
    int col = threadIdx.x;
    __shared__ float scq[32];
    if (col < 32) scq[col] = q_state[b * S_ + i * 32 + col];
    __syncthreads();

    unsigned short h[32];
    #pragma unroll
    for (int d = 0; d < 32; ++d) {
        int D = i * 32 + d;
        float v = fmaf(scq[d], W[(size_t)D * S_ + col], W[(size_t)(S_ + D) * S_ + col]);
        h[d] = f2bf_rn(v);
    }
    size_t base = (size_t)b * 262144 + (size_t)i * 16384 + (size_t)col * 8;
    #pragma unroll
    for (int kc = 0; kc < 4; ++kc) {
        uint4 H;
        H.x = h[kc*8+0] | ((unsigned)h[kc*8+1] << 16);
        H.y = h[kc*8+2] | ((unsigned)h[kc*8+3] << 16);
        H.z = h[kc*8+4] | ((unsigned)h[kc*8+5] << 16);
        H.w = h[kc*8+6] | ((unsigned)h[kc*8+7] << 16);
        *(uint4*)&Wc[base + kc * 4096] = H;
    }
}

// ---------------- Kernel PE: end-pass prep + fused start-finalize ----------
// Recomputes start argmax per block (deterministic), gathers u_s slice from
// es directly; i==0 blocks write pred_start/sp_ws; then folds W_qe -> Wc.
__global__ __launch_bounds__(512)
void prep_end_kernel(const float* __restrict__ W, const float* __restrict__ q_state,
                     const float* __restrict__ es, const float* __restrict__ start_scores,
                     const float* __restrict__ part,
                     int* __restrict__ sp_ws, float* __restrict__ pred_start,
                     short* __restrict__ Wc)
{
    int bid = blockIdx.x;
    int i = bid >> 6, b = bid & 63;
    int t = threadIdx.x, lane = t & 63, w = t >> 6;
    __shared__ float s_l[S_];
    __shared__ float wred[8];
    __shared__ int wcnt[8], cand[8];
    __shared__ float scq[32], scu[32];
    __shared__ int best_sh;

    s_l[t] = start_scores[b * S_ + t];
    __syncthreads();
    int cnt = select_cands(s_l, t, lane, w, wred, wcnt, cand);

    if (t == 0) {
        int bi = cand[0];
        if (cnt > 1) {
            float bv = -INFINITY;
            for (int c = 0; c < cnt; ++c) {
                float e = part[b * 8 + c];
                if (e > bv) { bv = e; bi = cand[c]; }
            }
        }
        best_sh = bi;
        if (i == 0) { pred_start[b] = (float)bi; sp_ws[b] = bi; }
    }
    __syncthreads();
    int best = best_sh;

    if (t < 32) scq[t] = q_state[b * S_ + i * 32 + t];
    if (t >= 32 && t < 64)
        scu[t - 32] = es[((size_t)(b * LS_ + best)) * S_ + i * 32 + (t - 32)];
    __syncthreads();

    int col = t;
    unsigned short h[32];
    #pragma unroll
    for (int d = 0; d < 32; ++d) {
        int D = i * 32 + d;
        float v = fmaf(scu[d], W[(size_t)D * S_ + col],
                  fmaf(scq[d], W[(size_t)(S_ + D) * S_ + col],
                       W[(size_t)(2 * S_ + D) * S_ + col]));
        h[d] = f2bf_rn(v);
    }
    size_t base = (size_t)b * 262144 + (size_t)i * 16384 + (size_t)col * 8;
    #pragma unroll
    for (int kc = 0; kc < 4; ++kc) {
        uint4 H;
        H.x = h[kc*8+0] | ((unsigned)h[kc*8+1] << 16);
        H.y = h[kc*8+2] | ((unsigned)h[kc*8+3] << 16);
        H.z = h[kc*8+4] | ((unsigned)h[kc*8+5] << 16);
        H.w = h[kc*8+6] | ((unsigned)h[kc*8+7] << 16);
        *(uint4*)&Wc[base + kc * 4096] = H;
    }
}

// -------- Kernel S: 128x512 bf16 MFMA score; depth-2 reg-staged B/A --------
// Grid 256 = 4rc x 64b XCD-grouped; 8 waves = 2wr x 4wc; wave 64r x 128c.
template <bool END>
__global__ __launch_bounds__(512)
void score_kernel(const float* __restrict__ es, const short* __restrict__ Wc,
                  const float* __restrict__ inter, const float* __restrict__ Wsmall,
                  const int* __restrict__ slen, const int* __restrict__ sp,
                  float* __restrict__ out)
{
    const int t = threadIdx.x;
    const int lane = t & 63, wid = t >> 6;
    const int wr = wid >> 2, wc = wid & 3;
    const int l15 = lane & 15, l4 = lane >> 4;

    int lid = blockIdx.x;
    int xcd = lid & 7, slot = lid >> 3;
    int b  = xcd * 8 + (slot >> 2);
    int rc = slot & 3;

    __shared__ __attribute__((aligned(16))) short As[2][4096];   // 16 KB
    __shared__ __attribute__((aligned(16))) short Bs[2][16384];  // 64 KB
    __shared__ float int_l[S_], wsm_l[S_];
    __shared__ float sm_red[128][4];

    int_l[t] = inter[b * S_ + t];
    wsm_l[t] = Wsmall[t];

    const char* Bbase = (const char*)(Wc + (size_t)b * 262144);

    f32x4 acc[4][8];
    #pragma unroll
    for (int r = 0; r < 4; ++r)
        #pragma unroll
        for (int c = 0; c < 8; ++c)
            acc[r][c] = (f32x4){0.f, 0.f, 0.f, 0.f};

    const int arow = t >> 2, akc = t & 3;
    const float* aptr = es + ((size_t)(b * LS_ + rc * 128 + arow)) * S_ + akc * 8;

    auto buildA = [&](int buf, float4 a0, float4 a1) {
        uint4 HA;
        HA.x = f2bf_rn(a0.x) | ((unsigned)f2bf_rn(a0.y) << 16);
        HA.y = f2bf_rn(a0.z) | ((unsigned)f2bf_rn(a0.w) << 16);
        HA.z = f2bf_rn(a1.x) | ((unsigned)f2bf_rn(a1.y) << 16);
        HA.w = f2bf_rn(a1.z) | ((unsigned)f2bf_rn(a1.w) << 16);
        *(uint4*)&As[buf][akc * 1024 + arow * 8] = HA;
    };
    auto mfma_step = [&](int buf) {
        bf16x8 ah[4];
        #pragma unroll
        for (int r = 0; r < 4; ++r) {
            int rowp = wr * 64 + r * 16 + l15;
            ah[r] = *(const bf16x8*)&As[buf][l4 * 1024 + rowp * 8];
        }
        #pragma unroll
        for (int c = 0; c < 8; ++c) {
            int col = wc * 128 + c * 16 + l15;
            bf16x8 bh = *(const bf16x8*)&Bs[buf][l4 * 4096 + col * 8];
            #pragma unroll
            for (int r = 0; r < 4; ++r)
                acc[r][c] = __builtin_amdgcn_mfma_f32_16x16x32_bf16(ah[r], bh, acc[r][c], 0, 0, 0);
        }
    };

    // prologue: tiles 0 (P) and 1 (Q) into registers — depth-2 pipeline
    uint4 P0, P1, P2, P3, Q0, Q1, Q2, Q3;
    {
        const char* gb = Bbase + t * 16;
        P0 = *(const uint4*)(gb);
        P1 = *(const uint4*)(gb + 8192);
        P2 = *(const uint4*)(gb + 16384);
        P3 = *(const uint4*)(gb + 24576);
        const char* gb1 = gb + 32768;
        Q0 = *(const uint4*)(gb1);
        Q1 = *(const uint4*)(gb1 + 8192);
        Q2 = *(const uint4*)(gb1 + 16384);
        Q3 = *(const uint4*)(gb1 + 24576);
    }
    float4 pa0 = *(const float4*)(aptr);
    float4 pa1 = *(const float4*)(aptr + 4);
    float4 qa0 = *(const float4*)(aptr + 32);
    float4 qa1 = *(const float4*)(aptr + 36);

    #pragma unroll 1
    for (int ii = 0; ii < 8; ++ii) {
        const int i = ii * 2;

        // ---- even sub-iter: tile i (P) -> buf 0 ----
        {
            char* lb = (char*)Bs[0] + t * 16;
            *(uint4*)(lb)         = P0;
            *(uint4*)(lb + 8192)  = P1;
            *(uint4*)(lb + 16384) = P2;
            *(uint4*)(lb + 24576) = P3;
        }
        buildA(0, pa0, pa1);
        if (i + 2 < 16) {
            const char* gb = Bbase + (size_t)(i + 2) * 32768 + t * 16;
            P0 = *(const uint4*)(gb);
            P1 = *(const uint4*)(gb + 8192);
            P2 = *(const uint4*)(gb + 16384);
            P3 = *(const uint4*)(gb + 24576);
            pa0 = *(const float4*)(aptr + (i + 2) * 32);
            pa1 = *(const float4*)(aptr + (i + 2) * 32 + 4);
        }
        asm volatile("s_waitcnt lgkmcnt(0)" ::: "memory");
        __builtin_amdgcn_s_barrier();
        mfma_step(0);

        // ---- odd sub-iter: tile i+1 (Q) -> buf 1 ----
        {
            char* lb = (char*)Bs[1] + t * 16;
            *(uint4*)(lb)         = Q0;
            *(uint4*)(lb + 8192)  = Q1;
            *(uint4*)(lb + 16384) = Q2;
            *(uint4*)(lb + 24576) = Q3;
        }
        buildA(1, qa0, qa1);
        if (i + 3 < 16) {
            const char* gb = Bbase + (size_t)(i + 3) * 32768 + t * 16;
            Q0 = *(const uint4*)(gb);
            Q1 = *(const uint4*)(gb + 8192);
            Q2 = *(const uint4*)(gb + 16384);
            Q3 = *(const uint4*)(gb + 24576);
            qa0 = *(const float4*)(aptr + (i + 3) * 32);
            qa1 = *(const float4*)(aptr + (i + 3) * 32 + 4);
        }
        asm volatile("s_waitcnt lgkmcnt(0)" ::: "memory");
        __builtin_amdgcn_s_barrier();
        mfma_step(1);
    }

    // epilogue: + inter, relu, dot Wsmall, row reduce, masks, store
    #pragma unroll
    for (int r = 0; r < 4; ++r) {
        #pragma unroll
        for (int jj = 0; jj < 4; ++jj) {
            float pr = 0.f;
            #pragma unroll
            for (int c = 0; c < 8; ++c) {
                int col = wc * 128 + c * 16 + l15;
                float v = acc[r][c][jj] + int_l[col];
                v = fmaxf(v, 0.f);
                pr = fmaf(v, wsm_l[col], pr);
            }
            pr += __shfl_xor(pr, 1);
            pr += __shfl_xor(pr, 2);
            pr += __shfl_xor(pr, 4);
            pr += __shfl_xor(pr, 8);
            if (l15 == 0) sm_red[wr * 64 + r * 16 + l4 * 4 + jj][wc] = pr;
        }
    }
    __syncthreads();
    if (t < 128) {
        int l = rc * 128 + t;
        float s = sm_red[t][0] + sm_red[t][1] + sm_red[t][2] + sm_red[t][3];
        if (l >= slen[b]) s += NEGV;
        if (END) { if (l < sp[b]) s += NEGV; }
        out[b * LS_ + l] = s;
    }
}

// ---------------- Kernel R: exact rescue, one candidate per block ----------
template <bool END>
__global__ __launch_bounds__(512)
void rescue_kernel(const float* __restrict__ support, const float* __restrict__ q_state,
                   const int* __restrict__ sp, const float* __restrict__ Wbig,
                   const float* __restrict__ inter, const float* __restrict__ Wsmall,
                   const float* __restrict__ scores, float* __restrict__ part)
{
    int bid = blockIdx.x;
    int b = bid >> 3, cslot = bid & 7;
    int t = threadIdx.x, lane = t & 63, w = t >> 6;
    __shared__ float s_l[S_], qs_l[S_], us_l[S_], arow_sh[S_];
    __shared__ float red[8][S_];
    __shared__ float wred[8];
    __shared__ int wcnt[8], cand[8];

    s_l[t]  = scores[b * S_ + t];
    qs_l[t] = q_state[b * S_ + t];
    if (END) {
        int spv = sp[b];
        us_l[t] = support[((size_t)(b * LS_ + spv)) * S_ + t];
    }
    __syncthreads();

    int cnt = select_cands(s_l, t, lane, w, wred, wcnt, cand);
    if (cnt == 1 || cslot >= cnt) return;

    int ci = cand[cslot];
    arow_sh[t] = support[((size_t)(b * LS_ + ci)) * S_ + t];
    __syncthreads();

    const float* W1 = Wbig;
    const float* W2 = Wbig + (size_t)S_ * S_;
    const float* W3 = Wbig + (size_t)2 * S_ * S_;
    const int d0 = w * 64;

    float z[8];
    #pragma unroll
    for (int j = 0; j < 8; ++j) z[j] = 0.f;

    #pragma unroll 2
    for (int dd = 0; dd < 64; ++dd) {
        int d = d0 + dd;
        float a  = arow_sh[d];
        float qa = qs_l[d] * a;
        float ua = END ? us_l[d] * a : 0.f;
        const float* r1 = W1 + (size_t)d * S_ + lane;
        const float* r2 = W2 + (size_t)d * S_ + lane;
        const float* r3 = W3 + (size_t)d * S_ + lane;
        #pragma unroll
        for (int j = 0; j < 8; ++j) {
            if (END)
                z[j] = fmaf(ua, r1[64 * j], fmaf(qa, r2[64 * j], fmaf(a, r3[64 * j], z[j])));
            else
                z[j] = fmaf(qa, r1[64 * j], fmaf(a, r2[64 * j], z[j]));
        }
    }
    #pragma unroll
    for (int j = 0; j < 8; ++j) red[w][lane + 64 * j] = z[j];
    __syncthreads();

    float v = 0.f;
    #pragma unroll
    for (int ww = 0; ww < 8; ++ww) v += red[ww][t];
    float p = fmaxf(v + inter[b * S_ + t], 0.f) * Wsmall[t];
    #pragma unroll
    for (int off = 32; off >= 1; off >>= 1)
        p += __shfl_xor(p, off);
    if (lane == 0) wred[w] = p;
    __syncthreads();
    if (t == 0) {
        float e = ((wred[0] + wred[1]) + (wred[2] + wred[3])) +
                  ((wred[4] + wred[5]) + (wred[6] + wred[7]));
        part[b * 8 + cslot] = e;
    }
}

// ---------------- Kernel F: finalize end pass (pred_end only) --------------
__global__ __launch_bounds__(512)
void finalize_end_kernel(const float* __restrict__ scores, const float* __restrict__ part,
                         float* __restrict__ pred)
{
    int b = blockIdx.x;
    int t = threadIdx.x, lane = t & 63, w = t >> 6;
    __shared__ float s_l[S_];
    __shared__ float wred[8];
    __shared__ int wcnt[8], cand[8];

    s_l[t] = scores[b * S_ + t];
    __syncthreads();
    int cnt = select_cands(s_l, t, lane, w, wred, wcnt, cand);

    if (t == 0) {
        int bi = cand[0];
        if (cnt > 1) {
            float bv = -INFINITY;
            for (int c = 0; c < cnt; ++c) {
                float e = part[b * 8 + c];
                if (e > bv) { bv = e; bi = cand[c]; }
            }
        }
        pred[b] = (float)bi;
    }
}

// ---------------- launch ----------------
extern "C" void kernel_launch(void* const* d_in, const int* in_sizes, int n_in,
                              void* d_out, int out_size, void* d_ws, size_t ws_size,
                              hipStream_t stream)
{
    const float* eq    = (const float*)d_in[0];
    const float* es    = (const float*)d_in[1];
    const int*   qlen  = (const int*)d_in[2];
    const int*   slen  = (const int*)d_in[3];
    const float* W_qa  = (const float*)d_in[7];
    const float* W_qsi = (const float*)d_in[8];
    const float* b_qsi = (const float*)d_in[9];
    const float* W_qs  = (const float*)d_in[10];
    const float* W_ss  = (const float*)d_in[11];
    const float* W_qei = (const float*)d_in[12];
    const float* b_qei = (const float*)d_in[13];
    const float* W_qe  = (const float*)d_in[14];
    const float* W_es  = (const float*)d_in[15];

    float* out          = (float*)d_out;
    float* start_scores = out;
    float* end_scores   = out + B_ * LS_;
    float* pred_start   = out + 2 * B_ * LS_;
    float* pred_end     = out + 2 * B_ * LS_ + B_;

    float* ws      = (float*)d_ws;
    float* q_state = ws;                       // [B,S]
    float* qsi     = ws + B_ * S_;             // [B,S]
    float* qei     = ws + 2 * B_ * S_;         // [B,S]
    float* part    = ws + 3 * B_ * S_;         // [B,8]
    int*   sp_ws   = (int*)(ws + 3 * B_ * S_ + 512);    // [B]
    short* Wc      = (short*)(ws + 3 * B_ * S_ + 1024); // 33.5 MB

    qpool_inter_kernel<<<dim3(B_, 2), 512, 0, stream>>>(
        eq, qlen, W_qa, W_qsi, b_qsi, W_qei, b_qei, q_state, qsi, qei);

    // ---- start pass ----
    prep_start_kernel<<<1024, 512, 0, stream>>>(W_qs, q_state, Wc);
    score_kernel<false><<<256, 512, 0, stream>>>(es, Wc, qsi, W_ss, slen, nullptr, start_scores);
    rescue_kernel<false><<<B_ * 8, 512, 0, stream>>>(es, q_state, nullptr, W_qs, qsi, W_ss,
                                                     start_scores, part);

    // ---- end pass (prep_end also finalizes the start pass) ----
    prep_end_kernel<<<1024, 512, 0, stream>>>(W_qe, q_state, es, start_scores, part,
                                              sp_ws, pred_start, Wc);
    score_kernel<true><<<256, 512, 0, stream>>>(es, Wc, qei, W_es, slen, sp_ws, end_scores);
    rescue_kernel<true><<<B_ * 8, 512, 0, stream>>>(es, q_state, sp_ws, W_qe, qei, W_es,
                                                    end_scores, part);
    finalize_end_kernel<<<B_, 512, 0, stream>>>(end_scores, part, pred_end);
}